// Round 1
// baseline (320.792 us; speedup 1.0000x reference)
//
#include <hip/hip_runtime.h>

#define N_ROWS 65536
#define DIMS 256
#define NCLS 64

// ---- ws float-index layout ----
#define P_SUM_S 0          // [8][64][256] partial sums, src
#define P_SUM_T 131072     // [8][64][256] partial sums, trg
#define P_CNT_S 262144     // [8][64]
#define P_CNT_T 262656     // [8][64]
#define ACC_OFF 263168     // double (2 floats), byte off 1052672 (8-aligned)
#define DONE_OFF 263170    // uint block-completion counter
#define RECIP_OFF 263172   // [3][64] reciprocal count tables
#define BPACK_OFF 263424   // bf16[8 s][8 mt][64 lane][8] = 64 KB = 16384 floats
#define BF16A_OFF 279808   // ushort[131072][256] bf16 feature copy = 64 MB
#define ZERO_FLOATS 263172 // memset covers partials + counts + acc + done

typedef __attribute__((ext_vector_type(8))) short bf16x8;
typedef __attribute__((ext_vector_type(4))) float f32x4;

__device__ __forceinline__ short f2bf(float f) {
  unsigned u = __float_as_uint(f);
  u += 0x7fffu + ((u >> 16) & 1u);  // round-to-nearest-even
  return (short)(u >> 16);
}

__device__ __forceinline__ float wave_sum64(float v) {
#pragma unroll
  for (int m = 32; m > 0; m >>= 1) v += __shfl_xor(v, m, 64);
  return v;
}
__device__ __forceinline__ float seg_max16(float v) {
#pragma unroll
  for (int m = 8; m > 0; m >>= 1) v = fmaxf(v, __shfl_xor(v, m, 64));
  return v;
}
__device__ __forceinline__ float seg_sum16(float v) {
#pragma unroll
  for (int m = 8; m > 0; m >>= 1) v += __shfl_xor(v, m, 64);
  return v;
}

// ---------------------------------------------------------------------------
// Kernel 1: per-class partial sums via LDS privatization + bf16 sidecar copy.
// 512 blocks (256 src, 256 trg), 256 rows/block, 8 partial buffers (blk&7).
// ---------------------------------------------------------------------------
__global__ __launch_bounds__(256) void seg_sum_kernel(
    const float* __restrict__ src_feat, const float* __restrict__ trg_feat,
    const int* __restrict__ src_label, const int* __restrict__ trg_label,
    float* __restrict__ ws_f) {
  __shared__ float lsum[NCLS * DIMS];  // 64 KB
  const int tid = threadIdx.x;
  const bool is_trg = blockIdx.x >= 256;
  const int blk = is_trg ? (blockIdx.x - 256) : blockIdx.x;
  const int part = blockIdx.x & 7;
  const float* feat = is_trg ? trg_feat : src_feat;
  const int* label = is_trg ? trg_label : src_label;
  float* gsum = ws_f + (is_trg ? P_SUM_T : P_SUM_S) + part * 16384;
  float* gcnt = ws_f + (is_trg ? P_CNT_T : P_CNT_S) + part * 64;
  unsigned short* bfA = (unsigned short*)(ws_f + BF16A_OFF);
  const size_t grow0 = (size_t)(is_trg ? N_ROWS : 0) + (size_t)blk * 256;

  for (int i = tid; i < NCLS * DIMS; i += 256) lsum[i] = 0.f;
  __syncthreads();

  const int row0 = blk * 256;
  float cnt_local = 0.f;
  for (int r = 0; r < 256; r += 8) {
    int lb[8];
    float v[8];
#pragma unroll
    for (int i = 0; i < 8; ++i) {
      lb[i] = label[row0 + r + i];
      v[i] = feat[(size_t)(row0 + r + i) * DIMS + tid];
    }
    // bf16 sidecar: row-major copy, 128B-contiguous per wave per row
#pragma unroll
    for (int i = 0; i < 8; ++i)
      bfA[(grow0 + r + i) * DIMS + tid] = (unsigned short)f2bf(v[i]);
#pragma unroll
    for (int i = 0; i < 8; ++i) {
      lsum[lb[i] * DIMS + tid] += v[i];
      if (tid < NCLS) cnt_local += (lb[i] == tid) ? 1.f : 0.f;
    }
  }
  __syncthreads();
  for (int c = 0; c < NCLS; ++c)
    atomicAdd(&gsum[c * DIMS + tid], lsum[c * DIMS + tid]);
  if (tid < NCLS) atomicAdd(&gcnt[tid], cnt_local);
}

// ---------------------------------------------------------------------------
// Kernel 2: reduce 8 partials inline + pack B fragments (RAW SUMS, not means)
// for mfma_f32_16x16x32_bf16, and write 1/cnt tables.
// B frag: lane l holds sum[class = tile*16 + (l&15)][k = s*32 + (l>>4)*8 + j].
// 8 blocks (mat*4+tile, mat in {0,1}) x 64 threads.
// ---------------------------------------------------------------------------
__global__ __launch_bounds__(64) void pack_kernel(float* __restrict__ ws_f) {
  const int bx = blockIdx.x;  // mat*4 + tile
  const int mat = bx >> 2;
  const int tile = bx & 3;
  const int lane = threadIdx.x;
  const int c = tile * 16 + (lane & 15);

  float cs = 0.f, ct = 0.f;
#pragma unroll
  for (int p = 0; p < 8; ++p) {
    cs += ws_f[P_CNT_S + p * 64 + c];
    ct += ws_f[P_CNT_T + p * 64 + c];
  }
  if (mat == 0 && lane < 16) {
    ws_f[RECIP_OFF + c] = 1.f / cs;
    ws_f[RECIP_OFF + 64 + c] = 1.f / ct;
    ws_f[RECIP_OFF + 128 + c] = 1.f / (cs + ct);
  }

  const float* sb = ws_f + (mat ? P_SUM_T : P_SUM_S) + c * DIMS;
  bf16x8* out = (bf16x8*)(ws_f + BPACK_OFF);

#pragma unroll
  for (int s = 0; s < 8; ++s) {
    const int k0 = s * 32 + (lane >> 4) * 8;
    float a8[8];
#pragma unroll
    for (int j = 0; j < 8; ++j) a8[j] = 0.f;
#pragma unroll
    for (int p = 0; p < 8; ++p) {
      const float4 lo = *(const float4*)(sb + p * 16384 + k0);
      const float4 hi = *(const float4*)(sb + p * 16384 + k0 + 4);
      a8[0] += lo.x; a8[1] += lo.y; a8[2] += lo.z; a8[3] += lo.w;
      a8[4] += hi.x; a8[5] += hi.y; a8[6] += hi.z; a8[7] += hi.w;
    }
    bf16x8 v;
#pragma unroll
    for (int j = 0; j < 8; ++j) v[j] = f2bf(a8[j]);
    out[(s * 8 + bx) * 64 + lane] = v;  // s-major: per-s B block is 8KB contiguous
  }
}

// ---------------------------------------------------------------------------
// Kernel 3: MFMA G_s,G_t (2 mats x 64 classes) from bf16 sidecar + derive
// 3 logit sets by per-class scaling + fused softmax/KL + device reduce +
// last-block finalize.
// 1024 blocks x 256 threads; 128 rows/block, 32 rows/wave (2 M-groups of 16).
// ---------------------------------------------------------------------------
__global__ __launch_bounds__(256, 4) void main_kernel(
    const float* __restrict__ ws_f, double* __restrict__ acc_out,
    float* __restrict__ out) {
  const int tid = threadIdx.x;
  const int wave = tid >> 6;
  const int lane = tid & 63;
  const int row0 = blockIdx.x * 128 + wave * 32;  // unified row (src then trg)
  const unsigned short* bfA = (const unsigned short*)(ws_f + BF16A_OFF);
  // A frag: row = row0 + g*16 + (lane&15), k = s*32 + (lane>>4)*8 + j
  const bf16x8* ap = (const bf16x8*)(bfA + (size_t)(row0 + (lane & 15)) * DIMS +
                                     (lane >> 4) * 8);
  const bf16x8* bp = (const bf16x8*)(ws_f + BPACK_OFF);

  // per-class reciprocal scales (4 class-tiles per lane)
  float rs[4], rt[4], rst[4];
#pragma unroll
  for (int t = 0; t < 4; ++t) {
    const int c = t * 16 + (lane & 15);
    rs[t] = ws_f[RECIP_OFF + c];
    rt[t] = ws_f[RECIP_OFF + 64 + c];
    rst[t] = ws_f[RECIP_OFF + 128 + c];
  }

  f32x4 C[2][4][2];
#pragma unroll
  for (int m = 0; m < 2; ++m)
#pragma unroll
    for (int t = 0; t < 4; ++t)
#pragma unroll
      for (int g = 0; g < 2; ++g) C[m][t][g] = (f32x4){0.f, 0.f, 0.f, 0.f};

#pragma unroll
  for (int s = 0; s < 8; ++s) {
    const bf16x8 a0 = ap[s * 4];        // g=0 rows
    const bf16x8 a1 = ap[512 + s * 4];  // g=1 rows (+16*32 bf16x8 units)
#pragma unroll
    for (int mt = 0; mt < 8; ++mt) {
      const bf16x8 b = bp[(s * 8 + mt) * 64 + lane];
      C[mt >> 2][mt & 3][0] = __builtin_amdgcn_mfma_f32_16x16x32_bf16(
          a0, b, C[mt >> 2][mt & 3][0], 0, 0, 0);
      C[mt >> 2][mt & 3][1] = __builtin_amdgcn_mfma_f32_16x16x32_bf16(
          a1, b, C[mt >> 2][mt & 3][1], 0, 0, 0);
    }
  }

  // Epilogue: D lane map: row = g*16 + (lane>>4)*4 + r, class = t*16 + (lane&15).
  // Logits: P_s = G_s/cs, P_t = G_t/ct, P_st = (G_s+G_t)/(cs+ct).
  float total = 0.f;
#pragma unroll
  for (int g = 0; g < 2; ++g) {
#pragma unroll
    for (int r = 0; r < 4; ++r) {
      float va[4], vb[4], vc[4];
#pragma unroll
      for (int t = 0; t < 4; ++t) {
        const float gs = C[0][t][g][r];
        const float gt = C[1][t][g][r];
        va[t] = gs * rs[t];
        vb[t] = gt * rt[t];
        vc[t] = (gs + gt) * rst[t];
      }
      float ma = fmaxf(fmaxf(va[0], va[1]), fmaxf(va[2], va[3]));
      float mb = fmaxf(fmaxf(vb[0], vb[1]), fmaxf(vb[2], vb[3]));
      float mc = fmaxf(fmaxf(vc[0], vc[1]), fmaxf(vc[2], vc[3]));
      ma = seg_max16(ma); mb = seg_max16(mb); mc = seg_max16(mc);
      float ea[4], eb[4], ec[4];
      float sa = 0.f, sb = 0.f, sc = 0.f;
#pragma unroll
      for (int t = 0; t < 4; ++t) {
        ea[t] = __expf(va[t] - ma); sa += ea[t];
        eb[t] = __expf(vb[t] - mb); sb += eb[t];
        ec[t] = __expf(vc[t] - mc); sc += ec[t];
      }
      sa = seg_sum16(sa); sb = seg_sum16(sb); sc = seg_sum16(sc);
      const float La = ma + __logf(sa);
      const float Lb = mb + __logf(sb);
      const float Lc = mc + __logf(sc);
      const float isa = 1.f / sa, isb = 1.f / sb, isc = 1.f / sc;
#pragma unroll
      for (int t = 0; t < 4; ++t) {
        const float la = va[t] - La, lb = vb[t] - Lb, lc = vc[t] - Lc;
        const float pa = ea[t] * isa, pb = eb[t] * isb, pc = ec[t] * isc;
        total += pa * ((la - lb) + (la - lc)) + pb * ((lb - la) + (lb - lc)) +
                 pc * ((lc - la) + (lc - lb));
      }
    }
  }
  total = wave_sum64(total);
  if (lane == 0) atomicAdd(acc_out, (double)total);

  // last-block finalize: final = sum_of_6_kl_sums / (6 * 2N * C)
  __syncthreads();
  if (tid == 0) {
    __threadfence();
    unsigned* done = (unsigned*)(ws_f + DONE_OFF);
    const unsigned old = atomicAdd(done, 1u);
    if (old == gridDim.x - 1) {
      const double a = atomicAdd(acc_out, 0.0);  // coherent read
      out[0] = (float)(a / 50331648.0);          // 6 * 131072 * 64
    }
  }
}

extern "C" void kernel_launch(void* const* d_in, const int* in_sizes, int n_in,
                              void* d_out, int out_size, void* d_ws, size_t ws_size,
                              hipStream_t stream) {
  const float* src_feat = (const float*)d_in[0];
  const float* trg_feat = (const float*)d_in[1];
  const int* src_label = (const int*)d_in[2];
  const int* trg_label = (const int*)d_in[3];
  // d_in[4] (trg_feat_un) unused by the reference loss.
  float* ws_f = (float*)d_ws;
  double* acc = (double*)(ws_f + ACC_OFF);
  float* out = (float*)d_out;

  // zero partial buffers + counts + accumulator + completion counter
  hipMemsetAsync(d_ws, 0, (size_t)ZERO_FLOATS * sizeof(float), stream);

  seg_sum_kernel<<<512, 256, 0, stream>>>(src_feat, trg_feat, src_label,
                                          trg_label, ws_f);
  pack_kernel<<<8, 64, 0, stream>>>(ws_f);
  main_kernel<<<1024, 256, 0, stream>>>(ws_f, acc, out);
}

// Round 2
// 252.741 us; speedup vs baseline: 1.2693x; 1.2693x over previous
//
#include <hip/hip_runtime.h>

#define N_ROWS 65536
#define DIMS 256
#define NCLS 64

// ---- ws float-index layout ----
#define P_SUM_S 0          // [8][64][256] partial sums, src
#define P_SUM_T 131072     // [8][64][256] partial sums, trg
#define P_CNT_S 262144     // [4][64]
#define P_CNT_T 262400     // [4][64]
#define ACC_OFF 262656     // double[64] slot accumulators (8B each, 512B total)
#define DONE_OFF 262784    // uint block-completion counter
#define RECIP_OFF 262788   // [3][64] reciprocal count tables
#define BPACK_OFF 262992   // bf16[8 s][8 mt][64 lane][8] = 64 KB (16B aligned)
#define BF16A_OFF 279376   // ushort[131072][256] bf16 feature copy = 64 MB
#define ZERO_FLOATS 262788 // memset covers partials + counts + acc + done

typedef __attribute__((ext_vector_type(8))) short bf16x8;
typedef __attribute__((ext_vector_type(4))) float f32x4;

__device__ __forceinline__ short f2bf(float f) {
  unsigned u = __float_as_uint(f);
  u += 0x7fffu + ((u >> 16) & 1u);  // round-to-nearest-even
  return (short)(u >> 16);
}

__device__ __forceinline__ float wave_sum64(float v) {
#pragma unroll
  for (int m = 32; m > 0; m >>= 1) v += __shfl_xor(v, m, 64);
  return v;
}
__device__ __forceinline__ double wave_sum64d(double v) {
#pragma unroll
  for (int m = 32; m > 0; m >>= 1) v += __shfl_xor(v, m, 64);
  return v;
}
__device__ __forceinline__ float seg_max16(float v) {
#pragma unroll
  for (int m = 8; m > 0; m >>= 1) v = fmaxf(v, __shfl_xor(v, m, 64));
  return v;
}
__device__ __forceinline__ float seg_sum16(float v) {
#pragma unroll
  for (int m = 8; m > 0; m >>= 1) v += __shfl_xor(v, m, 64);
  return v;
}

// async global->LDS, 16B per lane. LDS dest is wave-uniform base + lane*16.
__device__ __forceinline__ void gld16(const void* g, void* l) {
  __builtin_amdgcn_global_load_lds(
      (const __attribute__((address_space(1))) unsigned int*)g,
      (__attribute__((address_space(3))) unsigned int*)l, 16, 0, 0);
}

// ---------------------------------------------------------------------------
// Kernel 1: per-class partial sums via LDS privatization + bf16 sidecar copy.
// 512 blocks (256 src, 256 trg), 256 rows/block, 8 partial buffers (blk&7).
// ---------------------------------------------------------------------------
__global__ __launch_bounds__(256) void seg_sum_kernel(
    const float* __restrict__ src_feat, const float* __restrict__ trg_feat,
    const int* __restrict__ src_label, const int* __restrict__ trg_label,
    float* __restrict__ ws_f) {
  __shared__ float lsum[NCLS * DIMS];  // 64 KB
  const int tid = threadIdx.x;
  const bool is_trg = blockIdx.x >= 256;
  const int blk = is_trg ? (blockIdx.x - 256) : blockIdx.x;
  const int part = blockIdx.x & 7;
  const int part4 = blockIdx.x & 3;
  const float* feat = is_trg ? trg_feat : src_feat;
  const int* label = is_trg ? trg_label : src_label;
  float* gsum = ws_f + (is_trg ? P_SUM_T : P_SUM_S) + part * 16384;
  float* gcnt = ws_f + (is_trg ? P_CNT_T : P_CNT_S) + part4 * 64;
  unsigned short* bfA = (unsigned short*)(ws_f + BF16A_OFF);
  const size_t grow0 = (size_t)(is_trg ? N_ROWS : 0) + (size_t)blk * 256;

  for (int i = tid; i < NCLS * DIMS; i += 256) lsum[i] = 0.f;
  __syncthreads();

  const int row0 = blk * 256;
  float cnt_local = 0.f;
  for (int r = 0; r < 256; r += 8) {
    int lb[8];
    float v[8];
#pragma unroll
    for (int i = 0; i < 8; ++i) {
      lb[i] = label[row0 + r + i];
      v[i] = feat[(size_t)(row0 + r + i) * DIMS + tid];
    }
    // bf16 sidecar: row-major copy, 128B-contiguous per wave per row
#pragma unroll
    for (int i = 0; i < 8; ++i)
      bfA[(grow0 + r + i) * DIMS + tid] = (unsigned short)f2bf(v[i]);
#pragma unroll
    for (int i = 0; i < 8; ++i) {
      lsum[lb[i] * DIMS + tid] += v[i];
      if (tid < NCLS) cnt_local += (lb[i] == tid) ? 1.f : 0.f;
    }
  }
  __syncthreads();
  for (int c = 0; c < NCLS; ++c)
    atomicAdd(&gsum[c * DIMS + tid], lsum[c * DIMS + tid]);
  if (tid < NCLS) atomicAdd(&gcnt[tid], cnt_local);
}

// ---------------------------------------------------------------------------
// Kernel 2: reduce 8 partials inline + pack B fragments (RAW SUMS) for
// mfma_f32_16x16x32_bf16, plus 1/cnt tables.
// B frag: lane l holds sum[class = tile*16 + (l&15)][k = s*32 + (l>>4)*8 + j].
// 64 blocks (s*8 + mat*4 + tile) x 64 threads.
// ---------------------------------------------------------------------------
__global__ __launch_bounds__(64) void pack_kernel(float* __restrict__ ws_f) {
  const int bx = blockIdx.x;  // s*8 + mat*4 + tile
  const int s = bx >> 3;
  const int mt = bx & 7;
  const int mat = mt >> 2;
  const int tile = mt & 3;
  const int lane = threadIdx.x;
  const int c = tile * 16 + (lane & 15);

  if (s == 0 && mat == 0 && lane < 16) {
    float cs = 0.f, ct = 0.f;
#pragma unroll
    for (int p = 0; p < 4; ++p) {
      cs += ws_f[P_CNT_S + p * 64 + c];
      ct += ws_f[P_CNT_T + p * 64 + c];
    }
    ws_f[RECIP_OFF + c] = 1.f / cs;
    ws_f[RECIP_OFF + 64 + c] = 1.f / ct;
    ws_f[RECIP_OFF + 128 + c] = 1.f / (cs + ct);
  }

  const float* sb = ws_f + (mat ? P_SUM_T : P_SUM_S) + c * DIMS;
  const int k0 = s * 32 + (lane >> 4) * 8;
  float a8[8];
#pragma unroll
  for (int j = 0; j < 8; ++j) a8[j] = 0.f;
#pragma unroll
  for (int p = 0; p < 8; ++p) {
    const float4 lo = *(const float4*)(sb + p * 16384 + k0);
    const float4 hi = *(const float4*)(sb + p * 16384 + k0 + 4);
    a8[0] += lo.x; a8[1] += lo.y; a8[2] += lo.z; a8[3] += lo.w;
    a8[4] += hi.x; a8[5] += hi.y; a8[6] += hi.z; a8[7] += hi.w;
  }
  bf16x8 v;
#pragma unroll
  for (int j = 0; j < 8; ++j) v[j] = f2bf(a8[j]);
  ((bf16x8*)(ws_f + BPACK_OFF))[bx * 64 + lane] = v;
}

// ---------------------------------------------------------------------------
// Kernel 3: LDS-staged (double-buffered, global_load_lds) MFMA of G_s,G_t +
// derived 3 logit sets + fused softmax/KL + block-level atomic fan-in.
// 1024 blocks x 256 threads; 128 rows/block, 32 rows/wave.
// LDS per s-chunk: A = 128 rows x 32 k bf16 (8 KB), B = 8 frags x 1 KB (8 KB).
// A LDS layout: slot q = row*4 + kseg_lin, content kseg_g = kseg_lin ^ (row&3)
// (2-bit XOR swizzle, applied at stage-source AND ds_read).
// ---------------------------------------------------------------------------
__global__ __launch_bounds__(256, 4) void main_kernel(
    const float* __restrict__ ws_f, double* __restrict__ acc,
    unsigned* __restrict__ done, float* __restrict__ out) {
  __shared__ unsigned short abuf[2][4096];  // 2 x 8 KB
  __shared__ unsigned short bbuf[2][4096];  // 2 x 8 KB
  __shared__ double wsum[4];
  __shared__ unsigned lastflag;

  const int tid = threadIdx.x;
  const int w = tid >> 6;
  const int lane = tid & 63;
  const int row0 = blockIdx.x * 128;  // unified row space (src then trg)
  const unsigned short* bfA = (const unsigned short*)(ws_f + BF16A_OFF);
  const unsigned short* bpk = (const unsigned short*)(ws_f + BPACK_OFF);

  // staging source pointers (per-thread), s-offset added per chunk
  // A instr (w,j): lane covers row = w*32 + j*16 + (lane>>2), 16B seg
  // kseg_g = (lane&3) ^ ((lane>>2)&3) -> contiguous 64B per row at source
  const unsigned short* pa0 =
      bfA + (size_t)(row0 + w * 32 + (lane >> 2)) * DIMS +
      (((lane & 3) ^ ((lane >> 2) & 3)) * 8);
  const unsigned short* pa1 = pa0 + 16 * DIMS;
  // B instr (w,j): linear 16B segs, q' = (w*2+j)*64 + lane
  const unsigned short* pb0 = bpk + (size_t)(w * 128 + lane) * 8;
  const unsigned short* pb1 = pb0 + 512;

#define STAGE(ss, bb)                                         \
  {                                                           \
    gld16(pa0 + (ss) * 32, &abuf[bb][w * 1024]);              \
    gld16(pa1 + (ss) * 32, &abuf[bb][w * 1024 + 512]);        \
    gld16(pb0 + (ss) * 4096, &bbuf[bb][w * 1024]);            \
    gld16(pb1 + (ss) * 4096, &bbuf[bb][w * 1024 + 512]);      \
  }

  // per-class reciprocal scales (4 class-tiles per lane)
  float rs[4], rt[4], rst[4];
#pragma unroll
  for (int t = 0; t < 4; ++t) {
    const int c = t * 16 + (lane & 15);
    rs[t] = ws_f[RECIP_OFF + c];
    rt[t] = ws_f[RECIP_OFF + 64 + c];
    rst[t] = ws_f[RECIP_OFF + 128 + c];
  }

  f32x4 C[2][4][2];
#pragma unroll
  for (int m = 0; m < 2; ++m)
#pragma unroll
    for (int t = 0; t < 4; ++t)
#pragma unroll
      for (int g = 0; g < 2; ++g) C[m][t][g] = (f32x4){0.f, 0.f, 0.f, 0.f};

  STAGE(0, 0);
  __syncthreads();  // drains vmcnt -> buf0 ready

  // A-frag ds_read address (shorts): row_l = w*32 + g*16 + (lane&15),
  // slot = row_l*4 + ((lane>>4) ^ (row_l&3)); row_l&3 == lane&3.
  const int abase =
      (w * 32 + (lane & 15)) * 32 + (((lane >> 4) ^ (lane & 3)) * 8);

#pragma unroll
  for (int s = 0; s < 8; ++s) {
    const int cb = s & 1;
    if (s < 7) STAGE(s + 1, cb ^ 1);
    const bf16x8 a0 = *(const bf16x8*)&abuf[cb][abase];
    const bf16x8 a1 = *(const bf16x8*)&abuf[cb][abase + 512];
#pragma unroll
    for (int mt = 0; mt < 8; ++mt) {
      const bf16x8 b = *(const bf16x8*)&bbuf[cb][(mt * 64 + lane) * 8];
      C[mt >> 2][mt & 3][0] = __builtin_amdgcn_mfma_f32_16x16x32_bf16(
          a0, b, C[mt >> 2][mt & 3][0], 0, 0, 0);
      C[mt >> 2][mt & 3][1] = __builtin_amdgcn_mfma_f32_16x16x32_bf16(
          a1, b, C[mt >> 2][mt & 3][1], 0, 0, 0);
    }
    __syncthreads();  // reads of buf[cb] done; staging into cb^1 drained
  }
#undef STAGE

  // Epilogue: D lane map: row = g*16 + (lane>>4)*4 + r, class = t*16+(lane&15).
  // Logits: P_s = G_s/cs, P_t = G_t/ct, P_st = (G_s+G_t)/(cs+ct).
  float total = 0.f;
#pragma unroll
  for (int g = 0; g < 2; ++g) {
#pragma unroll
    for (int r = 0; r < 4; ++r) {
      float va[4], vb[4], vc[4];
#pragma unroll
      for (int t = 0; t < 4; ++t) {
        const float gs = C[0][t][g][r];
        const float gt = C[1][t][g][r];
        va[t] = gs * rs[t];
        vb[t] = gt * rt[t];
        vc[t] = (gs + gt) * rst[t];
      }
      float ma = fmaxf(fmaxf(va[0], va[1]), fmaxf(va[2], va[3]));
      float mb = fmaxf(fmaxf(vb[0], vb[1]), fmaxf(vb[2], vb[3]));
      float mc = fmaxf(fmaxf(vc[0], vc[1]), fmaxf(vc[2], vc[3]));
      ma = seg_max16(ma); mb = seg_max16(mb); mc = seg_max16(mc);
      float ea[4], eb[4], ec[4];
      float sa = 0.f, sb = 0.f, sc = 0.f;
#pragma unroll
      for (int t = 0; t < 4; ++t) {
        ea[t] = __expf(va[t] - ma); sa += ea[t];
        eb[t] = __expf(vb[t] - mb); sb += eb[t];
        ec[t] = __expf(vc[t] - mc); sc += ec[t];
      }
      sa = seg_sum16(sa); sb = seg_sum16(sb); sc = seg_sum16(sc);
      const float La = ma + __logf(sa);
      const float Lb = mb + __logf(sb);
      const float Lc = mc + __logf(sc);
      const float isa = 1.f / sa, isb = 1.f / sb, isc = 1.f / sc;
#pragma unroll
      for (int t = 0; t < 4; ++t) {
        const float la = va[t] - La, lb = vb[t] - Lb, lc = vc[t] - Lc;
        const float pa = ea[t] * isa, pb = eb[t] * isb, pc = ec[t] * isc;
        total += pa * ((la - lb) + (la - lc)) + pb * ((lb - la) + (lb - lc)) +
                 pc * ((lc - la) + (lc - lb));
      }
    }
  }
  total = wave_sum64(total);
  if (lane == 0) wsum[w] = (double)total;
  __syncthreads();

  // one f64 atomic per block into 64 spread slots; last block finalizes
  if (tid == 0) {
    const double bt = wsum[0] + wsum[1] + wsum[2] + wsum[3];
    atomicAdd(&acc[blockIdx.x & 63], bt);
    __threadfence();
    lastflag = (atomicAdd(done, 1u) == gridDim.x - 1) ? 1u : 0u;
  }
  __syncthreads();
  if (lastflag && tid < 64) {
    double v = atomicAdd(&acc[tid], 0.0);  // coherent read of slot
    v = wave_sum64d(v);
    if (tid == 0) out[0] = (float)(v / 50331648.0);  // 6 * 131072 * 64
  }
}

extern "C" void kernel_launch(void* const* d_in, const int* in_sizes, int n_in,
                              void* d_out, int out_size, void* d_ws, size_t ws_size,
                              hipStream_t stream) {
  const float* src_feat = (const float*)d_in[0];
  const float* trg_feat = (const float*)d_in[1];
  const int* src_label = (const int*)d_in[2];
  const int* trg_label = (const int*)d_in[3];
  // d_in[4] (trg_feat_un) unused by the reference loss.
  float* ws_f = (float*)d_ws;
  double* acc = (double*)(ws_f + ACC_OFF);
  unsigned* done = (unsigned*)(ws_f + DONE_OFF);
  float* out = (float*)d_out;

  // zero partial buffers + counts + acc slots + completion counter
  hipMemsetAsync(d_ws, 0, (size_t)ZERO_FLOATS * sizeof(float), stream);

  seg_sum_kernel<<<512, 256, 0, stream>>>(src_feat, trg_feat, src_label,
                                          trg_label, ws_f);
  pack_kernel<<<64, 64, 0, stream>>>(ws_f);
  main_kernel<<<1024, 256, 0, stream>>>(ws_f, acc, done, out);
}